// Round 8
// baseline (865.952 us; speedup 1.0000x reference)
//
#include <hip/hip_runtime.h>
#include <hip/hip_bf16.h>

typedef unsigned short u16;
typedef unsigned long long u64;
typedef __attribute__((ext_vector_type(4))) short short4v;
typedef __attribute__((ext_vector_type(8))) short short8;
typedef __attribute__((ext_vector_type(4))) float floatx4;

__device__ __forceinline__ u16 f2bf(float f) {
    union { float f; unsigned u; } v; v.f = f;
    unsigned r = v.u + 0x7FFF + ((v.u >> 16) & 1);
    return (u16)(r >> 16);
}

// ---------------------------------------------------------------------------
// Wcat stacks for both layers in one dispatch (grid 896 = 2 x 448).
// 7 slabs [B_0..B_5, selfW^T], K = 3584, fragment layout validated:
// element (k,n) at: (k>>5)*16384 + (n>>4)*512 + ((k>>3)&3)*128 + (n&15)*8 + (k&7)
__global__ void k_wcat2(const float* __restrict__ b0, const float* __restrict__ s0,
                        const float* __restrict__ b1, const float* __restrict__ s1,
                        u16* __restrict__ wf0, u16* __restrict__ wf1) {
    int bi = blockIdx.x, t = threadIdx.x;
    const float* basis = (bi < 448) ? b0 : b1;
    const float* selfW = (bi < 448) ? s0 : s1;
    u16* wf = (bi < 448) ? wf0 : wf1;
    if (bi >= 448) bi -= 448;
    int kr = t >> 7;             // 0..1
    int nb = (t & 127) * 4;      // n base
    for (int it = 0; it < 4; ++it) {
        int k = bi * 8 + it * 2 + kr;     // 0..3583
        float v0, v1, v2, v3;
        if (k < 3072) {
            int q = k >> 9, h = k & 511;
            const float4 bz = *(const float4*)(basis + ((size_t)(q * 512 + h)) * 512 + nb);
            v0 = bz.x; v1 = bz.y; v2 = bz.z; v3 = bz.w;
        } else {
            int kk = k - 3072;
            v0 = selfW[(size_t)(nb + 0) * 512 + kk];
            v1 = selfW[(size_t)(nb + 1) * 512 + kk];
            v2 = selfW[(size_t)(nb + 2) * 512 + kk];
            v3 = selfW[(size_t)(nb + 3) * 512 + kk];
        }
        float vv[4] = {v0, v1, v2, v3};
        for (int i = 0; i < 4; ++i) {
            int n = nb + i;
            wf[(size_t)(k >> 5) * 16384 + (n >> 4) * 512 + ((k >> 3) & 3) * 128 + (n & 15) * 8 + (k & 7)] = f2bf(vv[i]);
        }
    }
}

// ---------------------------------------------------------------------------
// Row masks via coalesced row reads + wave ballot (unchanged, validated).
__global__ void k_masks(const int* __restrict__ A, u64* __restrict__ m0, u64* __restrict__ m1) {
    int bi = blockIdx.x;          // b*12 + r
    int b = bi / 12, r = bi % 12;
    const int* Ab = A + (size_t)(b * 13 + (r + 1)) * 62 * 62;
    int lane = threadIdx.x;       // 0..63
    u64 my0 = 0, my1 = 0;
    for (int n = 0; n < 64; ++n) {
        int raw = 0;
        if (n < 62 && lane < 62) raw = (Ab[n * 62 + lane] != 0) ? 1 : 0;
        u64 b0 = __ballot(raw != 0);
        int v1 = 0;
        if (n < 63 && lane < 63) {
            int oi = (n == 62) ? 63 : n;
            int oj = (lane == 62) ? 63 : lane;
            v1 = (oi < 62 && oj < 62) ? raw : 0;
            int lo = (oi < oj) ? oi : oj, hi = (oi < oj) ? oj : oi;
            if (hi == lo + 2) {
                int p = (lo >> 1) & 1;
                int chp = ((lo & 1) == 0) ? (p ? 12 : 11) : (p ? 11 : 12);
                if (r + 1 == chp) v1 = 1;
            }
        }
        u64 b1 = __ballot(v1 != 0);
        if (lane == n) { my0 = b0; my1 = b1; }
    }
    m0[(size_t)bi * 64 + lane] = my0;
    m1[(size_t)bi * 64 + lane] = my1;
}

// ---------------------------------------------------------------------------
// Weighted adjacency expansion, ONE comb-set per dispatch (aqbuf regenerated
// per layer to fit workspace): A_q = sum_r comb[r][q] * adj_r -> bf16 frags.
__global__ void k_aqexp1(const u64* __restrict__ msk, const float* __restrict__ comb,
                         u16* __restrict__ aq) {
    int b = blockIdx.x >> 3, sp = blockIdx.x & 7;
    int t = threadIdx.x;
    __shared__ u64 sm[12 * 64];
    __shared__ float cmb[72];
    if (t < 72) cmb[t] = comb[t];
    for (int i = t; i < 768; i += 256) sm[i] = msk[(size_t)b * 768 + i];
    __syncthreads();
    #pragma unroll
    for (int ii2 = 0; ii2 < 2; ++ii2) {
        int pos = (sp * 2 + ii2) * 256 + t;
        int f = pos >> 9, lane = (pos >> 3) & 63, j = pos & 7;
        int row = ((f >> 1) << 4) + (lane & 15);
        int mb  = ((f & 1) << 5) + ((lane >> 4) << 3) + j;
        float bits[12];
        #pragma unroll
        for (int r = 0; r < 12; ++r) bits[r] = (float)((sm[r * 64 + row] >> mb) & 1ull);
        #pragma unroll
        for (int q = 0; q < 6; ++q) {
            float v = 0.f;
            #pragma unroll
            for (int r = 0; r < 12; ++r) v += bits[r] * cmb[r * 6 + q];
            aq[((size_t)b * 6 + q) * 4096 + pos] = f2bf(v);
        }
    }
}

// ---------------------------------------------------------------------------
// Fused cast + prep (saves a dispatch). Blocks 0..3839: enc f32 -> mi1 rows
// 0..59 / mi2 rows 0..57 (vectorized, validated). Blocks 3840..4095: initial
// embedding -> mi1 rows 60..63 ; mi2 rows 62,63 (validated).
__global__ void k_castprep(const float* __restrict__ enc,
                           const int* __restrict__ player,
                           const float* __restrict__ pAx, const float* __restrict__ pAy,
                           const float* __restrict__ pBx, const float* __restrict__ pBy,
                           const float* __restrict__ emb, const float* __restrict__ cW,
                           const float* __restrict__ cb, const float* __restrict__ inW,
                           const float* __restrict__ inb,
                           u16* __restrict__ mi1, u16* __restrict__ mi2) {
    int t = threadIdx.x;
    if (blockIdx.x < 3840) {
        long long e = ((long long)blockIdx.x * 256 + t) * 8;
        int b = (int)(e / (60 * 512));
        int rm = (int)(e % (60 * 512));
        int n = rm / 512, h = rm % 512;
        float4 f0 = *(const float4*)(enc + e);
        float4 f1 = *(const float4*)(enc + e + 4);
        short8 pk;
        pk[0] = (short)f2bf(f0.x); pk[1] = (short)f2bf(f0.y);
        pk[2] = (short)f2bf(f0.z); pk[3] = (short)f2bf(f0.w);
        pk[4] = (short)f2bf(f1.x); pk[5] = (short)f2bf(f1.y);
        pk[6] = (short)f2bf(f1.z); pk[7] = (short)f2bf(f1.w);
        *(short8*)(mi1 + ((size_t)b * 64 + n) * 512 + h) = pk;
        if (n < 58) *(short8*)(mi2 + ((size_t)b * 64 + n) * 512 + h) = pk;
        return;
    }
    int b = blockIdx.x - 3840;
    __shared__ float feat[2][64];
    if (t < 64) {
        int j = t >> 5, d = t & 31;
        float X = j ? pBx[b] : pAx[b];
        float Y = j ? pBy[b] : pAy[b];
        feat[j][d] = fmaxf(cW[d * 2] * X + cW[d * 2 + 1] * Y + cb[d], 0.f);
        feat[j][32 + d] = emb[player[b * 2 + j] * 32 + d];
    }
    __syncthreads();
    for (int h = t; h < 512; h += 256) {
        float a0 = inb[h], a1 = inb[h];
        const float* wrow = inW + h * 64;
        #pragma unroll
        for (int d = 0; d < 64; ++d) {
            float wv = wrow[d];
            a0 += wv * feat[0][d];
            a1 += wv * feat[1][d];
        }
        u16 v0 = f2bf(a0), v1 = f2bf(a1);
        size_t base = (size_t)b * 64 * 512;
        mi1[base + 60 * 512 + h] = v0;
        mi1[base + 61 * 512 + h] = v1;
        mi1[base + 62 * 512 + h] = 0;
        mi1[base + 63 * 512 + h] = 0;
        mi2[base + 62 * 512 + h] = v1;
        mi2[base + 63 * 512 + h] = 0;
    }
}

// ---------------------------------------------------------------------------
// Full RGCN layer, v13 = U-reassociation:
//   Y = relu( sum_q A_q @ (X @ B_q)  +  X @ selfW^T )
// All global GEMM reads are row-major X (A-operand, contiguous frags) or wcat
// frags — NO transposed gather. U_q goes through LDS in wcat-frag layout
// (write: contiguous short4, read: lane*8 contiguous), double-buffered.
// Block = (batch, col-half), 256 thr = 4 waves; wave w owns 64-col band.
// Epilogue writes outT (frag layout, for k_klast's B-operand) + rows 48..63
// row-major (k_klast's self slab) — x12's only consumers.
__global__ __launch_bounds__(256, 2)
void k_layer(const u16* __restrict__ x, const u16* __restrict__ aq,
             const u16* __restrict__ wc, u16* __restrict__ outT, u16* __restrict__ outR) {
    int b = blockIdx.x >> 1, nh = blockIdx.x & 1;
    int t = threadIdx.x, lane = t & 63, w = t >> 6;
    int l15 = lane & 15, lq = lane >> 4;
    __shared__ __align__(16) u16 U[2][16384];     // 2 x (2 k-slabs x 16 hfrags x 512)

    const u16* xrow  = x + (size_t)b * 64 * 512;
    const u16* aqb   = aq + (size_t)b * 6 * 4096 + (size_t)lane * 8;
    const u16* wbase = wc + (size_t)lane * 8;
    int cfb = nh * 16 + w * 4;                    // global col-frag base (wave: 4 frags)

    floatx4 accy[16];
    #pragma unroll
    for (int i = 0; i < 16; ++i) accy[i] = (floatx4)(0.f);

    // U_qq = X @ B_qq for the block's 256-col band -> U[buf] (wcat-frag layout)
    auto computeU = [&](int qq, int buf) {
        floatx4 au[16];
        #pragma unroll
        for (int i = 0; i < 16; ++i) au[i] = (floatx4)(0.f);
        for (int ks = 0; ks < 16; ++ks) {
            short8 af[4], bf[4];
            #pragma unroll
            for (int i = 0; i < 4; ++i)
                af[i] = *(const short8*)(xrow + (size_t)(i * 16 + l15) * 512 + ks * 32 + lq * 8);
            #pragma unroll
            for (int nt = 0; nt < 4; ++nt)
                bf[nt] = *(const short8*)(wbase + (size_t)(qq * 16 + ks) * 16384 + (size_t)(cfb + nt) * 512);
            #pragma unroll
            for (int i = 0; i < 4; ++i)
                #pragma unroll
                for (int nt = 0; nt < 4; ++nt)
                    au[i * 4 + nt] = __builtin_amdgcn_mfma_f32_16x16x32_bf16(af[i], bf[nt], au[i * 4 + nt], 0, 0, 0);
        }
        // C-layout (row m' = i*16+lq*4+reg, col hloc = (w*4+nt)*16+l15) -> frag layout
        #pragma unroll
        for (int i = 0; i < 4; ++i)
            #pragma unroll
            for (int nt = 0; nt < 4; ++nt) {
                short4v pk;
                #pragma unroll
                for (int reg = 0; reg < 4; ++reg) pk[reg] = (short)f2bf(au[i * 4 + nt][reg]);
                int a = (i >> 1) * 8192 + (w * 4 + nt) * 512 + ((i & 1) * 2 + (lq >> 1)) * 128 + l15 * 8 + (lq & 1) * 4;
                *(short4v*)&U[buf][a] = pk;
            }
    };

    // ---- prologue: U(0) + self slab (accy += X @ selfW^T, slab 6 of wcat)
    computeU(0, 0);
    for (int ks = 0; ks < 16; ++ks) {
        short8 af[4], bf[4];
        #pragma unroll
        for (int i = 0; i < 4; ++i)
            af[i] = *(const short8*)(xrow + (size_t)(i * 16 + l15) * 512 + ks * 32 + lq * 8);
        #pragma unroll
        for (int nt = 0; nt < 4; ++nt)
            bf[nt] = *(const short8*)(wbase + (size_t)(96 + ks) * 16384 + (size_t)(cfb + nt) * 512);
        #pragma unroll
        for (int i = 0; i < 4; ++i)
            #pragma unroll
            for (int nt = 0; nt < 4; ++nt)
                accy[i * 4 + nt] = __builtin_amdgcn_mfma_f32_16x16x32_bf16(af[i], bf[nt], accy[i * 4 + nt], 0, 0, 0);
    }
    __syncthreads();

    // ---- q loop, 1 barrier per q (U double-buffer)
    for (int q = 0; q < 6; ++q) {
        if (q < 5) computeU(q + 1, (q + 1) & 1);
        // accy += A_q @ U_q : A-op = aq frags (i*2+kk), B-op = U[q&1]
        #pragma unroll
        for (int kk = 0; kk < 2; ++kk) {
            short8 a_[4], ub[4];
            #pragma unroll
            for (int i = 0; i < 4; ++i)
                a_[i] = *(const short8*)(aqb + (size_t)q * 4096 + (i * 2 + kk) * 512);
            #pragma unroll
            for (int nt = 0; nt < 4; ++nt)
                ub[nt] = *(const short8*)&U[q & 1][kk * 8192 + (w * 4 + nt) * 512 + lane * 8];
            #pragma unroll
            for (int i = 0; i < 4; ++i)
                #pragma unroll
                for (int nt = 0; nt < 4; ++nt)
                    accy[i * 4 + nt] = __builtin_amdgcn_mfma_f32_16x16x32_bf16(a_[i], ub[nt], accy[i * 4 + nt], 0, 0, 0);
        }
        __syncthreads();
    }

    // ---- epilogue: relu; write frag-layout outT + rows 48..63 row-major outR
    #pragma unroll
    for (int i = 0; i < 4; ++i)
        #pragma unroll
        for (int nt = 0; nt < 4; ++nt) {
            short4v pk;
            #pragma unroll
            for (int reg = 0; reg < 4; ++reg) pk[reg] = (short)f2bf(fmaxf(accy[i * 4 + nt][reg], 0.f));
            size_t a = (size_t)b * 32768 + (i >> 1) * 16384 + (size_t)(nh * 16 + w * 4 + nt) * 512
                     + ((i & 1) * 2 + (lq >> 1)) * 128 + l15 * 8 + (lq & 1) * 4;
            *(short4v*)(outT + a) = pk;
            if (i == 3) {
                int n = nh * 256 + w * 64 + nt * 16 + l15;
                #pragma unroll
                for (int reg = 0; reg < 4; ++reg)
                    outR[((size_t)b * 16 + lq * 4 + reg) * 512 + n] = (u16)pk[reg];
            }
        }
}

// ---------------------------------------------------------------------------
// Final RGCN layer (output rows 48..63 only), v13: T-form with fragment-layout
// X input (from k_layer's outT — no scalar gather) + rows 48..63 row-major
// (self slab). Block = (batch, col-half), 4 waves; T double-buffered.
__global__ __launch_bounds__(256, 2)
void k_klast(const u16* __restrict__ xT, const u16* __restrict__ xr,
             const u16* __restrict__ aq, const u16* __restrict__ wc, int mode,
             u16* __restrict__ o16, float* __restrict__ o32) {
    int b = blockIdx.x >> 1, nh = blockIdx.x & 1;
    int t = threadIdx.x, lane = t & 63, w = t >> 6;
    int l15 = lane & 15, lq = lane >> 4;
    const int TS = 520;
    __shared__ __align__(16) u16 T[2][16 * 520];   // 33,280 B

    const u16* xTb   = xT + (size_t)b * 32768;
    const u16* aqb   = aq + (size_t)b * 6 * 4096 + (size_t)lane * 8;
    const u16* wbase = wc + (size_t)lane * 8;
    int cfb = nh * 16 + w * 4;

    // X as B-operand frags: slab kh, hfrag = w*8+nf (wave h-band = w*128)
    short8 xb[16];
    #pragma unroll
    for (int nf = 0; nf < 8; ++nf)
        #pragma unroll
        for (int kh = 0; kh < 2; ++kh)
            xb[nf * 2 + kh] = *(const short8*)(xTb + kh * 16384 + (size_t)(w * 8 + nf) * 512 + (size_t)lane * 8);

    floatx4 acc[4];
    #pragma unroll
    for (int i = 0; i < 4; ++i) acc[i] = (floatx4)(0.f);

    // self slab: rows 48..63 row-major (xr) x wcat slab 6
    for (int ks = 0; ks < 16; ++ks) {
        short8 af = *(const short8*)(xr + ((size_t)b * 16 + l15) * 512 + ks * 32 + lq * 8);
        #pragma unroll
        for (int nt = 0; nt < 4; ++nt) {
            short8 bf = *(const short8*)(wbase + (size_t)(96 + ks) * 16384 + (size_t)(cfb + nt) * 512);
            acc[nt] = __builtin_amdgcn_mfma_f32_16x16x32_bf16(af, bf, acc[nt], 0, 0, 0);
        }
    }

    // stage A: T'_q = A_q[48:64] @ X (aq frags 6,7), wave h-band w*128
    auto stageA = [&](int qq, int buf) {
        short8 a0 = *(const short8*)(aqb + (size_t)qq * 4096 + 6 * 512);
        short8 a1 = *(const short8*)(aqb + (size_t)qq * 4096 + 7 * 512);
        #pragma unroll
        for (int nf = 0; nf < 8; ++nf) {
            floatx4 tz = (floatx4)(0.f);
            tz = __builtin_amdgcn_mfma_f32_16x16x32_bf16(a0, xb[nf * 2 + 0], tz, 0, 0, 0);
            tz = __builtin_amdgcn_mfma_f32_16x16x32_bf16(a1, xb[nf * 2 + 1], tz, 0, 0, 0);
            int hcol = w * 128 + nf * 16 + l15;
            #pragma unroll
            for (int reg = 0; reg < 4; ++reg)
                T[buf][(lq * 4 + reg) * TS + hcol] = f2bf(tz[reg]);
        }
    };

    stageA(0, 0);
    __syncthreads();
    for (int q = 0; q < 6; ++q) {
        if (q < 5) stageA(q + 1, (q + 1) & 1);
        // stage B: acc += T'_q @ B_q (wave's 64-col band)
        for (int ks = 0; ks < 16; ++ks) {
            short8 af = *(const short8*)&T[q & 1][l15 * TS + ks * 32 + lq * 8];
            #pragma unroll
            for (int nt = 0; nt < 4; ++nt) {
                short8 bf = *(const short8*)(wbase + (size_t)(q * 16 + ks) * 16384 + (size_t)(cfb + nt) * 512);
                acc[nt] = __builtin_amdgcn_mfma_f32_16x16x32_bf16(af, bf, acc[nt], 0, 0, 0);
            }
        }
        __syncthreads();
    }

    // epilogue: m = 48 + lq*4 + reg, n = nh*256 + w*64 + nt*16 + l15
    #pragma unroll
    for (int nt = 0; nt < 4; ++nt) {
        int n = nh * 256 + w * 64 + nt * 16 + l15;
        #pragma unroll
        for (int reg = 0; reg < 4; ++reg) {
            int m = 48 + lq * 4 + reg;
            float v = acc[nt][reg];
            if (mode == 1) {
                if (m >= 58 && m <= 61)
                    o16[((size_t)b * 64 + m) * 512 + n] = f2bf(1.f / (1.f + __expf(-v)));
            } else {
                if (m == 60 || m == 62) {
                    int slot = (m == 60) ? (b * 2) : (b * 2 + 1);
                    o32[(size_t)slot * 512 + n] = 1.f / (1.f + __expf(-v));
                }
            }
        }
    }
}

// logits = [black|white] @ type_W^T + type_b  (unchanged, validated)
__global__ void k_final(const float* __restrict__ t2, const float* __restrict__ tW,
                        const float* __restrict__ tb, float* __restrict__ outp) {
    int b = blockIdx.x, l = threadIdx.x;   // 64 threads
    float a[11];
    #pragma unroll
    for (int j = 0; j < 11; ++j) a[j] = 0.f;
    for (int it = 0; it < 16; ++it) {
        int h = it * 64 + l;
        float c = (h < 512) ? t2[(b * 2 + 1) * 512 + h] : t2[(b * 2 + 0) * 512 + (h - 512)];
        #pragma unroll
        for (int j = 0; j < 11; ++j) a[j] += c * tW[j * 1024 + h];
    }
    #pragma unroll
    for (int j = 0; j < 11; ++j) {
        float v = a[j];
        for (int off = 32; off > 0; off >>= 1) v += __shfl_down(v, off, 64);
        if (l == 0) outp[b * 11 + j] = v + tb[j];
    }
}

// ---------------------------------------------------------------------------
extern "C" void kernel_launch(void* const* d_in, const int* in_sizes, int n_in,
                              void* d_out, int out_size, void* d_ws, size_t ws_size,
                              hipStream_t stream) {
    const int*   player = (const int*)d_in[0];
    const float* enc    = (const float*)d_in[2];
    const int*   adjm   = (const int*)d_in[3];
    const float* pAx    = (const float*)d_in[4];
    const float* pAy    = (const float*)d_in[5];
    const float* pBx    = (const float*)d_in[6];
    const float* pBy    = (const float*)d_in[7];
    const float* emb    = (const float*)d_in[8];
    const float* cW     = (const float*)d_in[9];
    const float* cb     = (const float*)d_in[10];
    const float* inW    = (const float*)d_in[11];
    const float* inb    = (const float*)d_in[12];
    const float* basis0 = (const float*)d_in[13];
    const float* comb0  = (const float*)d_in[14];
    const float* self0  = (const float*)d_in[15];
    const float* basis1 = (const float*)d_in[16];
    const float* comb1  = (const float*)d_in[17];
    const float* self1  = (const float*)d_in[18];
    const float* typeW  = (const float*)d_in[19];
    const float* typeb  = (const float*)d_in[20];

    char* ws = (char*)d_ws;
    size_t off = 0;
    auto alloc = [&](size_t bytes) -> void* {
        void* p = ws + off;
        off = (off + bytes + 255) & ~(size_t)255;
        return p;
    };
    // Workspace (~77.7 MB, well under proven 89):
    //   mi1 (prep..L1), aliased by t2 (L4..final)
    //   x12T/x12r: layer output (frag + rows48-63), reused by both passes
    //   aqbuf: ONE comb-set, regenerated before each layer dispatch
    u16* mi1   = (u16*)alloc(256UL * 64 * 512 * 2);
    u16* mi2   = (u16*)alloc(256UL * 64 * 512 * 2);
    u16* x12T  = (u16*)alloc(256UL * 32768 * 2);
    u16* x12r  = (u16*)alloc(256UL * 16 * 512 * 2);
    u16* aqbuf = (u16*)alloc(256UL * 6 * 4096 * 2);
    u16* wcat0 = (u16*)alloc(3584UL * 512 * 2);
    u16* wcat1 = (u16*)alloc(3584UL * 512 * 2);
    u64* mm0   = (u64*)alloc(256UL * 12 * 64 * 8);
    u64* mm1   = (u64*)alloc(256UL * 12 * 64 * 8);
    float* t2  = (float*)mi1;     // mi1 dead after L1

    k_wcat2<<<896, 256, 0, stream>>>(basis0, self0, basis1, self1, wcat0, wcat1);
    k_masks<<<3072, 64, 0, stream>>>(adjm, mm0, mm1);
    k_aqexp1<<<2048, 256, 0, stream>>>(mm0, comb0, aqbuf);
    k_castprep<<<4096, 256, 0, stream>>>(enc, player, pAx, pAy, pBx, pBy, emb, cW, cb, inW, inb, mi1, mi2);

    // pass 1
    k_layer<<<512, 256, 0, stream>>>(mi1, aqbuf, wcat0, x12T, x12r);
    k_aqexp1<<<2048, 256, 0, stream>>>(mm0, comb1, aqbuf);
    k_klast<<<512, 256, 0, stream>>>(x12T, x12r, aqbuf, wcat1, 1, mi2, nullptr);
    // pass 2
    k_aqexp1<<<2048, 256, 0, stream>>>(mm1, comb0, aqbuf);
    k_layer<<<512, 256, 0, stream>>>(mi2, aqbuf, wcat0, x12T, x12r);
    k_aqexp1<<<2048, 256, 0, stream>>>(mm1, comb1, aqbuf);
    k_klast<<<512, 256, 0, stream>>>(x12T, x12r, aqbuf, wcat1, 2, nullptr, t2);

    k_final<<<256, 64, 0, stream>>>(t2, typeW, typeb, (float*)d_out);
}

// Round 10
// 723.348 us; speedup vs baseline: 1.1971x; 1.1971x over previous
//
#include <hip/hip_runtime.h>
#include <hip/hip_bf16.h>

typedef unsigned short u16;
typedef unsigned long long u64;
typedef __attribute__((ext_vector_type(4))) short short4v;
typedef __attribute__((ext_vector_type(8))) short short8;
typedef __attribute__((ext_vector_type(4))) float floatx4;

__device__ __forceinline__ u16 f2bf(float f) {
    union { float f; unsigned u; } v; v.f = f;
    unsigned r = v.u + 0x7FFF + ((v.u >> 16) & 1);
    return (u16)(r >> 16);
}

// ---------------------------------------------------------------------------
// Wcat stacks for both layers in one dispatch (validated round 8).
// element (k,n) at: (k>>5)*16384 + (n>>4)*512 + ((k>>3)&3)*128 + (n&15)*8 + (k&7)
__global__ void k_wcat2(const float* __restrict__ b0, const float* __restrict__ s0,
                        const float* __restrict__ b1, const float* __restrict__ s1,
                        u16* __restrict__ wf0, u16* __restrict__ wf1) {
    int bi = blockIdx.x, t = threadIdx.x;
    const float* basis = (bi < 448) ? b0 : b1;
    const float* selfW = (bi < 448) ? s0 : s1;
    u16* wf = (bi < 448) ? wf0 : wf1;
    if (bi >= 448) bi -= 448;
    int kr = t >> 7;
    int nb = (t & 127) * 4;
    for (int it = 0; it < 4; ++it) {
        int k = bi * 8 + it * 2 + kr;
        float v0, v1, v2, v3;
        if (k < 3072) {
            int q = k >> 9, h = k & 511;
            const float4 bz = *(const float4*)(basis + ((size_t)(q * 512 + h)) * 512 + nb);
            v0 = bz.x; v1 = bz.y; v2 = bz.z; v3 = bz.w;
        } else {
            int kk = k - 3072;
            v0 = selfW[(size_t)(nb + 0) * 512 + kk];
            v1 = selfW[(size_t)(nb + 1) * 512 + kk];
            v2 = selfW[(size_t)(nb + 2) * 512 + kk];
            v3 = selfW[(size_t)(nb + 3) * 512 + kk];
        }
        float vv[4] = {v0, v1, v2, v3};
        for (int i = 0; i < 4; ++i) {
            int n = nb + i;
            wf[(size_t)(k >> 5) * 16384 + (n >> 4) * 512 + ((k >> 3) & 3) * 128 + (n & 15) * 8 + (k & 7)] = f2bf(vv[i]);
        }
    }
}

// ---------------------------------------------------------------------------
// Row masks via coalesced row reads + wave ballot (unchanged, validated).
__global__ void k_masks(const int* __restrict__ A, u64* __restrict__ m0, u64* __restrict__ m1) {
    int bi = blockIdx.x;          // b*12 + r
    int b = bi / 12, r = bi % 12;
    const int* Ab = A + (size_t)(b * 13 + (r + 1)) * 62 * 62;
    int lane = threadIdx.x;       // 0..63
    u64 my0 = 0, my1 = 0;
    for (int n = 0; n < 64; ++n) {
        int raw = 0;
        if (n < 62 && lane < 62) raw = (Ab[n * 62 + lane] != 0) ? 1 : 0;
        u64 b0 = __ballot(raw != 0);
        int v1 = 0;
        if (n < 63 && lane < 63) {
            int oi = (n == 62) ? 63 : n;
            int oj = (lane == 62) ? 63 : lane;
            v1 = (oi < 62 && oj < 62) ? raw : 0;
            int lo = (oi < oj) ? oi : oj, hi = (oi < oj) ? oj : oi;
            if (hi == lo + 2) {
                int p = (lo >> 1) & 1;
                int chp = ((lo & 1) == 0) ? (p ? 12 : 11) : (p ? 11 : 12);
                if (r + 1 == chp) v1 = 1;
            }
        }
        u64 b1 = __ballot(v1 != 0);
        if (lane == n) { my0 = b0; my1 = b1; }
    }
    m0[(size_t)bi * 64 + lane] = my0;
    m1[(size_t)bi * 64 + lane] = my1;
}

// ---------------------------------------------------------------------------
// Weighted adjacency expansion (validated):
//   set 0 (comb0, full 8 frags)  -> aq0[(b*6+q)*4096 + pos]
//   set 1 (comb1, frags 6,7 only)-> aq1[(b*6+q)*1024 + pos-3072]
__global__ void k_aqexp(const u64* __restrict__ msk, const float* __restrict__ comb0,
                        const float* __restrict__ comb1, u16* __restrict__ aq0,
                        u16* __restrict__ aq1) {
    int b = blockIdx.x >> 3, sp = blockIdx.x & 7;
    int t = threadIdx.x;
    __shared__ u64 sm[12 * 64];
    __shared__ float cmb[2][12][6];
    if (t < 72) { cmb[0][t / 6][t % 6] = comb0[t]; cmb[1][t / 6][t % 6] = comb1[t]; }
    for (int i = t; i < 768; i += 256) sm[i] = msk[(size_t)b * 768 + i];
    __syncthreads();
    #pragma unroll
    for (int ii2 = 0; ii2 < 2; ++ii2) {
        int pos = (sp * 2 + ii2) * 256 + t;
        int f = pos >> 9, lane = (pos >> 3) & 63, j = pos & 7;
        int row = ((f >> 1) << 4) + (lane & 15);
        int mb  = ((f & 1) << 5) + ((lane >> 4) << 3) + j;
        float bits[12];
        #pragma unroll
        for (int r = 0; r < 12; ++r) bits[r] = (float)((sm[r * 64 + row] >> mb) & 1ull);
        #pragma unroll
        for (int q = 0; q < 6; ++q) {
            float v0 = 0.f, v1 = 0.f;
            #pragma unroll
            for (int r = 0; r < 12; ++r) {
                v0 += bits[r] * cmb[0][r][q];
                v1 += bits[r] * cmb[1][r][q];
            }
            aq0[((size_t)b * 6 + q) * 4096 + pos] = f2bf(v0);
            if (f >= 6) aq1[((size_t)b * 6 + q) * 1024 + pos - 3072] = f2bf(v1);
        }
    }
}

// ---------------------------------------------------------------------------
// Fused cast + prep (validated round 8).
__global__ void k_castprep(const float* __restrict__ enc,
                           const int* __restrict__ player,
                           const float* __restrict__ pAx, const float* __restrict__ pAy,
                           const float* __restrict__ pBx, const float* __restrict__ pBy,
                           const float* __restrict__ emb, const float* __restrict__ cW,
                           const float* __restrict__ cb, const float* __restrict__ inW,
                           const float* __restrict__ inb,
                           u16* __restrict__ mi1, u16* __restrict__ mi2) {
    int t = threadIdx.x;
    if (blockIdx.x < 3840) {
        long long e = ((long long)blockIdx.x * 256 + t) * 8;
        int b = (int)(e / (60 * 512));
        int rm = (int)(e % (60 * 512));
        int n = rm / 512, h = rm % 512;
        float4 f0 = *(const float4*)(enc + e);
        float4 f1 = *(const float4*)(enc + e + 4);
        short8 pk;
        pk[0] = (short)f2bf(f0.x); pk[1] = (short)f2bf(f0.y);
        pk[2] = (short)f2bf(f0.z); pk[3] = (short)f2bf(f0.w);
        pk[4] = (short)f2bf(f1.x); pk[5] = (short)f2bf(f1.y);
        pk[6] = (short)f2bf(f1.z); pk[7] = (short)f2bf(f1.w);
        *(short8*)(mi1 + ((size_t)b * 64 + n) * 512 + h) = pk;
        if (n < 58) *(short8*)(mi2 + ((size_t)b * 64 + n) * 512 + h) = pk;
        return;
    }
    int b = blockIdx.x - 3840;
    __shared__ float feat[2][64];
    if (t < 64) {
        int j = t >> 5, d = t & 31;
        float X = j ? pBx[b] : pAx[b];
        float Y = j ? pBy[b] : pAy[b];
        feat[j][d] = fmaxf(cW[d * 2] * X + cW[d * 2 + 1] * Y + cb[d], 0.f);
        feat[j][32 + d] = emb[player[b * 2 + j] * 32 + d];
    }
    __syncthreads();
    for (int h = t; h < 512; h += 256) {
        float a0 = inb[h], a1 = inb[h];
        const float* wrow = inW + h * 64;
        #pragma unroll
        for (int d = 0; d < 64; ++d) {
            float wv = wrow[d];
            a0 += wv * feat[0][d];
            a1 += wv * feat[1][d];
        }
        u16 v0 = f2bf(a0), v1 = f2bf(a1);
        size_t base = (size_t)b * 64 * 512;
        mi1[base + 60 * 512 + h] = v0;
        mi1[base + 61 * 512 + h] = v1;
        mi1[base + 62 * 512 + h] = 0;
        mi1[base + 63 * 512 + h] = 0;
        mi2[base + 62 * 512 + h] = v1;
        mi2[base + 63 * 512 + h] = 0;
    }
}

// ---------------------------------------------------------------------------
// Full RGCN layer — EXACT round-5 v10 structure (proven 99.5 µs), epilogue
// writes outT (fragment layout, round-8-validated formula) + outR rows 48..63.
__global__ __launch_bounds__(512, 2)
void k_layer(const u16* __restrict__ x, const u16* __restrict__ aq,
             const u16* __restrict__ wc, u16* __restrict__ outT, u16* __restrict__ outR) {
    int b = blockIdx.x >> 1, nh = blockIdx.x & 1;
    int t = threadIdx.x, lane = t & 63, w = t >> 6;
    int l15 = lane & 15, lq = lane >> 4;
    const int TS = 520;
    __shared__ __align__(16) u16 T[64 * 520];

    const u16* xb_base = x + (size_t)b * 64 * 512;
    short8 xb[8];
    #pragma unroll
    for (int nt = 0; nt < 4; ++nt)
        #pragma unroll
        for (int kh = 0; kh < 2; ++kh) {
            int h = (w * 4 + nt) * 16 + l15;
            int j0 = kh * 32 + lq * 8;
            short8 v;
            #pragma unroll
            for (int jj = 0; jj < 8; ++jj)
                v[jj] = (short)xb_base[(size_t)(j0 + jj) * 512 + h];
            xb[nt * 2 + kh] = v;
        }

    floatx4 acc[8];                          // [i 0..3][nt 0..1]
    #pragma unroll
    for (int i = 0; i < 8; ++i) acc[i] = (floatx4)(0.f);

    const u16* aqb   = aq + (size_t)b * 6 * 4096 + (size_t)lane * 8;
    const u16* wbase = wc + (size_t)lane * 8;
    int cf0 = nh * 16 + w * 2;

    for (int q = 0; q < 6; ++q) {
        __syncthreads();
        // ---- stage A: T_q[m][h-band w] (full T, duplicated per col-half)
        for (int i = 0; i < 4; ++i) {
            short8 a0 = *(const short8*)(aqb + (size_t)q * 4096 + (i * 2 + 0) * 512);
            short8 a1 = *(const short8*)(aqb + (size_t)q * 4096 + (i * 2 + 1) * 512);
            #pragma unroll
            for (int nt = 0; nt < 4; ++nt) {
                floatx4 tz = (floatx4)(0.f);
                tz = __builtin_amdgcn_mfma_f32_16x16x32_bf16(a0, xb[nt * 2 + 0], tz, 0, 0, 0);
                tz = __builtin_amdgcn_mfma_f32_16x16x32_bf16(a1, xb[nt * 2 + 1], tz, 0, 0, 0);
                int hcol = (w * 4 + nt) * 16 + l15;
                int mrow = i * 16 + lq * 4;
                #pragma unroll
                for (int reg = 0; reg < 4; ++reg)
                    T[(mrow + reg) * TS + hcol] = f2bf(tz[reg]);
            }
        }
        __syncthreads();
        // ---- stage B: acc += T_q @ B_q  (own 32-col band)
        for (int ks = 0; ks < 16; ++ks) {
            short8 af[4], bf[2];
            #pragma unroll
            for (int i = 0; i < 4; ++i)
                af[i] = *(const short8*)&T[(i * 16 + l15) * TS + ks * 32 + lq * 8];
            #pragma unroll
            for (int nt = 0; nt < 2; ++nt)
                bf[nt] = *(const short8*)(wbase + (size_t)(q * 16 + ks) * 16384 + (size_t)(cf0 + nt) * 512);
            #pragma unroll
            for (int i = 0; i < 4; ++i)
                #pragma unroll
                for (int nt = 0; nt < 2; ++nt)
                    acc[i * 2 + nt] = __builtin_amdgcn_mfma_f32_16x16x32_bf16(af[i], bf[nt], acc[i * 2 + nt], 0, 0, 0);
        }
    }
    // ---- slab 6: self term
    for (int ks = 0; ks < 16; ++ks) {
        short8 af[4], bf[2];
        #pragma unroll
        for (int i = 0; i < 4; ++i)
            af[i] = *(const short8*)(xb_base + (size_t)(i * 16 + l15) * 512 + ks * 32 + lq * 8);
        #pragma unroll
        for (int nt = 0; nt < 2; ++nt)
            bf[nt] = *(const short8*)(wbase + (size_t)(96 + ks) * 16384 + (size_t)(cf0 + nt) * 512);
        #pragma unroll
        for (int i = 0; i < 4; ++i)
            #pragma unroll
            for (int nt = 0; nt < 2; ++nt)
                acc[i * 2 + nt] = __builtin_amdgcn_mfma_f32_16x16x32_bf16(af[i], bf[nt], acc[i * 2 + nt], 0, 0, 0);
    }
    // ---- epilogue: relu -> outT (frag layout) + outR (rows 48..63 row-major)
    #pragma unroll
    for (int i = 0; i < 4; ++i)
        #pragma unroll
        for (int nt = 0; nt < 2; ++nt) {
            short4v pk;
            #pragma unroll
            for (int reg = 0; reg < 4; ++reg) pk[reg] = (short)f2bf(fmaxf(acc[i * 2 + nt][reg], 0.f));
            size_t a = (size_t)b * 32768 + (size_t)(i >> 1) * 16384 + (size_t)(cf0 + nt) * 512
                     + (size_t)((i & 1) * 2 + (lq >> 1)) * 128 + (size_t)l15 * 8 + (lq & 1) * 4;
            *(short4v*)(outT + a) = pk;
            if (i == 3) {
                int n = nh * 256 + w * 32 + nt * 16 + l15;
                #pragma unroll
                for (int reg = 0; reg < 4; ++reg)
                    outR[((size_t)b * 16 + lq * 4 + reg) * 512 + n] = (u16)pk[reg];
            }
        }
}

// ---------------------------------------------------------------------------
// Final RGCN layer (rows 48..63), v15: ONE WAVE per (batch, 64-col band).
// Fix vs v14: the C-layout -> A-frag transpose goes through a 1.25 KB LDS
// scratch (the bpermute version was impossible: each src lane would have to
// serve 8 distinct reg/tile values). Single wave -> barriers are ~free.
//   write: tp[m = lq*4+reg][hloc = tile*16 + l15]
//   read:  af = tp[l15][lq*8 .. lq*8+7]  (contiguous short8, 16B-aligned)
__global__ __launch_bounds__(64)
void k_klast(const u16* __restrict__ xT, const u16* __restrict__ xr,
             const u16* __restrict__ aq1, const u16* __restrict__ wc, int mode,
             u16* __restrict__ o16, float* __restrict__ o32) {
    int b = blockIdx.x >> 3, cb = blockIdx.x & 7;
    int lane = threadIdx.x;
    int l15 = lane & 15, lq = lane >> 4;
    const int PS = 40;                         // tp row stride (16B-aligned reads)
    __shared__ __align__(16) u16 tp[16 * 40];  // 1280 B

    const u16* xTb   = xT + (size_t)b * 32768 + (size_t)lane * 8;
    const u16* wbase = wc + (size_t)lane * 8;
    const u16* aqb   = aq1 + (size_t)b * 6 * 1024 + (size_t)lane * 8;

    // preload A_q rows-48..63 frags (frag6: k 0..31, frag7: k 32..63)
    short8 aqf[12];
    #pragma unroll
    for (int q = 0; q < 6; ++q) {
        aqf[q * 2 + 0] = *(const short8*)(aqb + (size_t)q * 1024);
        aqf[q * 2 + 1] = *(const short8*)(aqb + (size_t)q * 1024 + 512);
    }

    floatx4 acc[4];
    #pragma unroll
    for (int i = 0; i < 4; ++i) acc[i] = (floatx4)(0.f);

    // self slab: xr rows 48..63 row-major x wcat slab 6 (validated pattern)
    for (int ks = 0; ks < 16; ++ks) {
        short8 af = *(const short8*)(xr + ((size_t)b * 16 + l15) * 512 + ks * 32 + lq * 8);
        #pragma unroll
        for (int nt = 0; nt < 4; ++nt) {
            short8 bf = *(const short8*)(wbase + (size_t)(96 + ks) * 16384 + (size_t)(cb * 4 + nt) * 512);
            acc[nt] = __builtin_amdgcn_mfma_f32_16x16x32_bf16(af, bf, acc[nt], 0, 0, 0);
        }
    }

    for (int p = 0; p < 16; ++p) {      // h-pair = 32 h-cols = stage-B k-frag p
        // xb frags for h-tiles 2p, 2p+1 (coalesced, round-8-validated layout)
        short8 xb00 = *(const short8*)(xTb + (size_t)(2 * p + 0) * 512);
        short8 xb01 = *(const short8*)(xTb + 16384 + (size_t)(2 * p + 0) * 512);
        short8 xb10 = *(const short8*)(xTb + (size_t)(2 * p + 1) * 512);
        short8 xb11 = *(const short8*)(xTb + 16384 + (size_t)(2 * p + 1) * 512);
        for (int q = 0; q < 6; ++q) {
            // stage A: two C-tiles of T'_q (rows 0..15 = nodes 48..63)
            floatx4 tz0 = (floatx4)(0.f), tz1 = (floatx4)(0.f);
            tz0 = __builtin_amdgcn_mfma_f32_16x16x32_bf16(aqf[q * 2 + 0], xb00, tz0, 0, 0, 0);
            tz0 = __builtin_amdgcn_mfma_f32_16x16x32_bf16(aqf[q * 2 + 1], xb01, tz0, 0, 0, 0);
            tz1 = __builtin_amdgcn_mfma_f32_16x16x32_bf16(aqf[q * 2 + 0], xb10, tz1, 0, 0, 0);
            tz1 = __builtin_amdgcn_mfma_f32_16x16x32_bf16(aqf[q * 2 + 1], xb11, tz1, 0, 0, 0);
            // C layout: tz_t[reg] = T'[m = lq*4+reg][h = 32p + t*16 + l15]
            #pragma unroll
            for (int reg = 0; reg < 4; ++reg) {
                tp[(lq * 4 + reg) * PS + l15]      = f2bf(tz0[reg]);
                tp[(lq * 4 + reg) * PS + 16 + l15] = f2bf(tz1[reg]);
            }
            __syncthreads();   // 1-wave: cheap; order writes before read
            short8 af = *(const short8*)&tp[l15 * PS + lq * 8];
            __syncthreads();   // read done before next q overwrites
            // stage B: acc += T'_q[:, 32p..32p+31] @ B_q[k-frag p, col band]
            #pragma unroll
            for (int nt = 0; nt < 4; ++nt) {
                short8 bf = *(const short8*)(wbase + (size_t)(q * 16 + p) * 16384 + (size_t)(cb * 4 + nt) * 512);
                acc[nt] = __builtin_amdgcn_mfma_f32_16x16x32_bf16(af, bf, acc[nt], 0, 0, 0);
            }
        }
    }

    // epilogue (validated): m = 48 + lq*4 + reg, n = cb*64 + nt*16 + l15
    #pragma unroll
    for (int nt = 0; nt < 4; ++nt) {
        int n = cb * 64 + nt * 16 + l15;
        #pragma unroll
        for (int reg = 0; reg < 4; ++reg) {
            int m = 48 + lq * 4 + reg;
            float v = acc[nt][reg];
            if (mode == 1) {
                if (m >= 58 && m <= 61)
                    o16[((size_t)b * 64 + m) * 512 + n] = f2bf(1.f / (1.f + __expf(-v)));
            } else {
                if (m == 60 || m == 62) {
                    int slot = (m == 60) ? (b * 2) : (b * 2 + 1);
                    o32[(size_t)slot * 512 + n] = 1.f / (1.f + __expf(-v));
                }
            }
        }
    }
}

// logits = [black|white] @ type_W^T + type_b  (unchanged, validated)
__global__ void k_final(const float* __restrict__ t2, const float* __restrict__ tW,
                        const float* __restrict__ tb, float* __restrict__ outp) {
    int b = blockIdx.x, l = threadIdx.x;   // 64 threads
    float a[11];
    #pragma unroll
    for (int j = 0; j < 11; ++j) a[j] = 0.f;
    for (int it = 0; it < 16; ++it) {
        int h = it * 64 + l;
        float c = (h < 512) ? t2[(b * 2 + 1) * 512 + h] : t2[(b * 2 + 0) * 512 + (h - 512)];
        #pragma unroll
        for (int j = 0; j < 11; ++j) a[j] += c * tW[j * 1024 + h];
    }
    #pragma unroll
    for (int j = 0; j < 11; ++j) {
        float v = a[j];
        for (int off = 32; off > 0; off >>= 1) v += __shfl_down(v, off, 64);
        if (l == 0) outp[b * 11 + j] = v + tb[j];
    }
}

// ---------------------------------------------------------------------------
extern "C" void kernel_launch(void* const* d_in, const int* in_sizes, int n_in,
                              void* d_out, int out_size, void* d_ws, size_t ws_size,
                              hipStream_t stream) {
    const int*   player = (const int*)d_in[0];
    const float* enc    = (const float*)d_in[2];
    const int*   adjm   = (const int*)d_in[3];
    const float* pAx    = (const float*)d_in[4];
    const float* pAy    = (const float*)d_in[5];
    const float* pBx    = (const float*)d_in[6];
    const float* pBy    = (const float*)d_in[7];
    const float* emb    = (const float*)d_in[8];
    const float* cW     = (const float*)d_in[9];
    const float* cb     = (const float*)d_in[10];
    const float* inW    = (const float*)d_in[11];
    const float* inb    = (const float*)d_in[12];
    const float* basis0 = (const float*)d_in[13];
    const float* comb0  = (const float*)d_in[14];
    const float* self0  = (const float*)d_in[15];
    const float* basis1 = (const float*)d_in[16];
    const float* comb1  = (const float*)d_in[17];
    const float* self1  = (const float*)d_in[18];
    const float* typeW  = (const float*)d_in[19];
    const float* typeb  = (const float*)d_in[20];

    char* ws = (char*)d_ws;
    size_t off = 0;
    auto alloc = [&](size_t bytes) -> void* {
        void* p = ws + off;
        off = (off + bytes + 255) & ~(size_t)255;
        return p;
    };
    // Workspace (~80.8 MB, under proven 89.1):
    //   mi1 (prep..layer1), aliased by t2 (klast2..final)
    //   x12T/x12r: layer->klast frag + rows48-63, reused both passes
    //   aq0 full (k_layer), aq1 compact frags 6,7 (klast); regenerated mid-run
    u16* mi1   = (u16*)alloc(256UL * 64 * 512 * 2);
    u16* mi2   = (u16*)alloc(256UL * 64 * 512 * 2);
    u16* x12T  = (u16*)alloc(256UL * 32768 * 2);
    u16* x12r  = (u16*)alloc(256UL * 16 * 512 * 2);
    u16* aq0   = (u16*)alloc(256UL * 6 * 4096 * 2);
    u16* aq1   = (u16*)alloc(256UL * 6 * 1024 * 2);
    u16* wcat0 = (u16*)alloc(3584UL * 512 * 2);
    u16* wcat1 = (u16*)alloc(3584UL * 512 * 2);
    u64* mm0   = (u64*)alloc(256UL * 12 * 64 * 8);
    u64* mm1   = (u64*)alloc(256UL * 12 * 64 * 8);
    float* t2  = (float*)mi1;     // mi1 dead after pass-1 k_layer

    k_wcat2<<<896, 256, 0, stream>>>(basis0, self0, basis1, self1, wcat0, wcat1);
    k_masks<<<3072, 64, 0, stream>>>(adjm, mm0, mm1);
    k_aqexp<<<2048, 256, 0, stream>>>(mm0, comb0, comb1, aq0, aq1);
    k_castprep<<<4096, 256, 0, stream>>>(enc, player, pAx, pAy, pBx, pBy, emb, cW, cb, inW, inb, mi1, mi2);

    // pass 1
    k_layer<<<512, 512, 0, stream>>>(mi1, aq0, wcat0, x12T, x12r);
    k_klast<<<2048, 64, 0, stream>>>(x12T, x12r, aq1, wcat1, 1, mi2, nullptr);
    // regenerate weighted adjacency for the pruned pass-2 graph
    k_aqexp<<<2048, 256, 0, stream>>>(mm1, comb0, comb1, aq0, aq1);
    // pass 2
    k_layer<<<512, 512, 0, stream>>>(mi2, aq0, wcat0, x12T, x12r);
    k_klast<<<2048, 64, 0, stream>>>(x12T, x12r, aq1, wcat1, 2, nullptr, t2);

    k_final<<<256, 64, 0, stream>>>(t2, typeW, typeb, (float*)d_out);
}

// Round 11
// 717.097 us; speedup vs baseline: 1.2076x; 1.0087x over previous
//
#include <hip/hip_runtime.h>
#include <hip/hip_bf16.h>

typedef unsigned short u16;
typedef unsigned long long u64;
typedef __attribute__((ext_vector_type(4))) short short4v;
typedef __attribute__((ext_vector_type(8))) short short8;
typedef __attribute__((ext_vector_type(4))) float floatx4;

__device__ __forceinline__ u16 f2bf(float f) {
    union { float f; unsigned u; } v; v.f = f;
    unsigned r = v.u + 0x7FFF + ((v.u >> 16) & 1);
    return (u16)(r >> 16);
}

// ---------------------------------------------------------------------------
// Wcat stacks for both layers in one dispatch (validated round 8).
// element (k,n) at: (k>>5)*16384 + (n>>4)*512 + ((k>>3)&3)*128 + (n&15)*8 + (k&7)
__global__ void k_wcat2(const float* __restrict__ b0, const float* __restrict__ s0,
                        const float* __restrict__ b1, const float* __restrict__ s1,
                        u16* __restrict__ wf0, u16* __restrict__ wf1) {
    int bi = blockIdx.x, t = threadIdx.x;
    const float* basis = (bi < 448) ? b0 : b1;
    const float* selfW = (bi < 448) ? s0 : s1;
    u16* wf = (bi < 448) ? wf0 : wf1;
    if (bi >= 448) bi -= 448;
    int kr = t >> 7;
    int nb = (t & 127) * 4;
    for (int it = 0; it < 4; ++it) {
        int k = bi * 8 + it * 2 + kr;
        float v0, v1, v2, v3;
        if (k < 3072) {
            int q = k >> 9, h = k & 511;
            const float4 bz = *(const float4*)(basis + ((size_t)(q * 512 + h)) * 512 + nb);
            v0 = bz.x; v1 = bz.y; v2 = bz.z; v3 = bz.w;
        } else {
            int kk = k - 3072;
            v0 = selfW[(size_t)(nb + 0) * 512 + kk];
            v1 = selfW[(size_t)(nb + 1) * 512 + kk];
            v2 = selfW[(size_t)(nb + 2) * 512 + kk];
            v3 = selfW[(size_t)(nb + 3) * 512 + kk];
        }
        float vv[4] = {v0, v1, v2, v3};
        for (int i = 0; i < 4; ++i) {
            int n = nb + i;
            wf[(size_t)(k >> 5) * 16384 + (n >> 4) * 512 + ((k >> 3) & 3) * 128 + (n & 15) * 8 + (k & 7)] = f2bf(vv[i]);
        }
    }
}

// ---------------------------------------------------------------------------
// Row masks via coalesced row reads + wave ballot (unchanged, validated).
__global__ void k_masks(const int* __restrict__ A, u64* __restrict__ m0, u64* __restrict__ m1) {
    int bi = blockIdx.x;          // b*12 + r
    int b = bi / 12, r = bi % 12;
    const int* Ab = A + (size_t)(b * 13 + (r + 1)) * 62 * 62;
    int lane = threadIdx.x;       // 0..63
    u64 my0 = 0, my1 = 0;
    for (int n = 0; n < 64; ++n) {
        int raw = 0;
        if (n < 62 && lane < 62) raw = (Ab[n * 62 + lane] != 0) ? 1 : 0;
        u64 b0 = __ballot(raw != 0);
        int v1 = 0;
        if (n < 63 && lane < 63) {
            int oi = (n == 62) ? 63 : n;
            int oj = (lane == 62) ? 63 : lane;
            v1 = (oi < 62 && oj < 62) ? raw : 0;
            int lo = (oi < oj) ? oi : oj, hi = (oi < oj) ? oj : oi;
            if (hi == lo + 2) {
                int p = (lo >> 1) & 1;
                int chp = ((lo & 1) == 0) ? (p ? 12 : 11) : (p ? 11 : 12);
                if (r + 1 == chp) v1 = 1;
            }
        }
        u64 b1 = __ballot(v1 != 0);
        if (lane == n) { my0 = b0; my1 = b1; }
    }
    m0[(size_t)bi * 64 + lane] = my0;
    m1[(size_t)bi * 64 + lane] = my1;
}

// ---------------------------------------------------------------------------
// Weighted adjacency expansion (validated):
//   set 0 (comb0, full 8 frags)  -> aq0[(b*6+q)*4096 + pos]
//   set 1 (comb1, frags 6,7 only)-> aq1[(b*6+q)*1024 + pos-3072]
__global__ void k_aqexp(const u64* __restrict__ msk, const float* __restrict__ comb0,
                        const float* __restrict__ comb1, u16* __restrict__ aq0,
                        u16* __restrict__ aq1) {
    int b = blockIdx.x >> 3, sp = blockIdx.x & 7;
    int t = threadIdx.x;
    __shared__ u64 sm[12 * 64];
    __shared__ float cmb[2][12][6];
    if (t < 72) { cmb[0][t / 6][t % 6] = comb0[t]; cmb[1][t / 6][t % 6] = comb1[t]; }
    for (int i = t; i < 768; i += 256) sm[i] = msk[(size_t)b * 768 + i];
    __syncthreads();
    #pragma unroll
    for (int ii2 = 0; ii2 < 2; ++ii2) {
        int pos = (sp * 2 + ii2) * 256 + t;
        int f = pos >> 9, lane = (pos >> 3) & 63, j = pos & 7;
        int row = ((f >> 1) << 4) + (lane & 15);
        int mb  = ((f & 1) << 5) + ((lane >> 4) << 3) + j;
        float bits[12];
        #pragma unroll
        for (int r = 0; r < 12; ++r) bits[r] = (float)((sm[r * 64 + row] >> mb) & 1ull);
        #pragma unroll
        for (int q = 0; q < 6; ++q) {
            float v0 = 0.f, v1 = 0.f;
            #pragma unroll
            for (int r = 0; r < 12; ++r) {
                v0 += bits[r] * cmb[0][r][q];
                v1 += bits[r] * cmb[1][r][q];
            }
            aq0[((size_t)b * 6 + q) * 4096 + pos] = f2bf(v0);
            if (f >= 6) aq1[((size_t)b * 6 + q) * 1024 + pos - 3072] = f2bf(v1);
        }
    }
}

// ---------------------------------------------------------------------------
// Fused cast + prep (validated round 8).
__global__ void k_castprep(const float* __restrict__ enc,
                           const int* __restrict__ player,
                           const float* __restrict__ pAx, const float* __restrict__ pAy,
                           const float* __restrict__ pBx, const float* __restrict__ pBy,
                           const float* __restrict__ emb, const float* __restrict__ cW,
                           const float* __restrict__ cb, const float* __restrict__ inW,
                           const float* __restrict__ inb,
                           u16* __restrict__ mi1, u16* __restrict__ mi2) {
    int t = threadIdx.x;
    if (blockIdx.x < 3840) {
        long long e = ((long long)blockIdx.x * 256 + t) * 8;
        int b = (int)(e / (60 * 512));
        int rm = (int)(e % (60 * 512));
        int n = rm / 512, h = rm % 512;
        float4 f0 = *(const float4*)(enc + e);
        float4 f1 = *(const float4*)(enc + e + 4);
        short8 pk;
        pk[0] = (short)f2bf(f0.x); pk[1] = (short)f2bf(f0.y);
        pk[2] = (short)f2bf(f0.z); pk[3] = (short)f2bf(f0.w);
        pk[4] = (short)f2bf(f1.x); pk[5] = (short)f2bf(f1.y);
        pk[6] = (short)f2bf(f1.z); pk[7] = (short)f2bf(f1.w);
        *(short8*)(mi1 + ((size_t)b * 64 + n) * 512 + h) = pk;
        if (n < 58) *(short8*)(mi2 + ((size_t)b * 64 + n) * 512 + h) = pk;
        return;
    }
    int b = blockIdx.x - 3840;
    __shared__ float feat[2][64];
    if (t < 64) {
        int j = t >> 5, d = t & 31;
        float X = j ? pBx[b] : pAx[b];
        float Y = j ? pBy[b] : pAy[b];
        feat[j][d] = fmaxf(cW[d * 2] * X + cW[d * 2 + 1] * Y + cb[d], 0.f);
        feat[j][32 + d] = emb[player[b * 2 + j] * 32 + d];
    }
    __syncthreads();
    for (int h = t; h < 512; h += 256) {
        float a0 = inb[h], a1 = inb[h];
        const float* wrow = inW + h * 64;
        #pragma unroll
        for (int d = 0; d < 64; ++d) {
            float wv = wrow[d];
            a0 += wv * feat[0][d];
            a1 += wv * feat[1][d];
        }
        u16 v0 = f2bf(a0), v1 = f2bf(a1);
        size_t base = (size_t)b * 64 * 512;
        mi1[base + 60 * 512 + h] = v0;
        mi1[base + 61 * 512 + h] = v1;
        mi1[base + 62 * 512 + h] = 0;
        mi1[base + 63 * 512 + h] = 0;
        mi2[base + 62 * 512 + h] = v1;
        mi2[base + 63 * 512 + h] = 0;
    }
}

// ---------------------------------------------------------------------------
// Full RGCN layer — EXACT round-5 v10 structure (proven 99.5 µs), epilogue
// writes outT (fragment layout, round-8-validated formula) + outR rows 48..63.
__global__ __launch_bounds__(512, 2)
void k_layer(const u16* __restrict__ x, const u16* __restrict__ aq,
             const u16* __restrict__ wc, u16* __restrict__ outT, u16* __restrict__ outR) {
    int b = blockIdx.x >> 1, nh = blockIdx.x & 1;
    int t = threadIdx.x, lane = t & 63, w = t >> 6;
    int l15 = lane & 15, lq = lane >> 4;
    const int TS = 520;
    __shared__ __align__(16) u16 T[64 * 520];

    const u16* xb_base = x + (size_t)b * 64 * 512;
    short8 xb[8];
    #pragma unroll
    for (int nt = 0; nt < 4; ++nt)
        #pragma unroll
        for (int kh = 0; kh < 2; ++kh) {
            int h = (w * 4 + nt) * 16 + l15;
            int j0 = kh * 32 + lq * 8;
            short8 v;
            #pragma unroll
            for (int jj = 0; jj < 8; ++jj)
                v[jj] = (short)xb_base[(size_t)(j0 + jj) * 512 + h];
            xb[nt * 2 + kh] = v;
        }

    floatx4 acc[8];                          // [i 0..3][nt 0..1]
    #pragma unroll
    for (int i = 0; i < 8; ++i) acc[i] = (floatx4)(0.f);

    const u16* aqb   = aq + (size_t)b * 6 * 4096 + (size_t)lane * 8;
    const u16* wbase = wc + (size_t)lane * 8;
    int cf0 = nh * 16 + w * 2;

    for (int q = 0; q < 6; ++q) {
        __syncthreads();
        // ---- stage A: T_q[m][h-band w] (full T, duplicated per col-half)
        for (int i = 0; i < 4; ++i) {
            short8 a0 = *(const short8*)(aqb + (size_t)q * 4096 + (i * 2 + 0) * 512);
            short8 a1 = *(const short8*)(aqb + (size_t)q * 4096 + (i * 2 + 1) * 512);
            #pragma unroll
            for (int nt = 0; nt < 4; ++nt) {
                floatx4 tz = (floatx4)(0.f);
                tz = __builtin_amdgcn_mfma_f32_16x16x32_bf16(a0, xb[nt * 2 + 0], tz, 0, 0, 0);
                tz = __builtin_amdgcn_mfma_f32_16x16x32_bf16(a1, xb[nt * 2 + 1], tz, 0, 0, 0);
                int hcol = (w * 4 + nt) * 16 + l15;
                int mrow = i * 16 + lq * 4;
                #pragma unroll
                for (int reg = 0; reg < 4; ++reg)
                    T[(mrow + reg) * TS + hcol] = f2bf(tz[reg]);
            }
        }
        __syncthreads();
        // ---- stage B: acc += T_q @ B_q  (own 32-col band)
        for (int ks = 0; ks < 16; ++ks) {
            short8 af[4], bf[2];
            #pragma unroll
            for (int i = 0; i < 4; ++i)
                af[i] = *(const short8*)&T[(i * 16 + l15) * TS + ks * 32 + lq * 8];
            #pragma unroll
            for (int nt = 0; nt < 2; ++nt)
                bf[nt] = *(const short8*)(wbase + (size_t)(q * 16 + ks) * 16384 + (size_t)(cf0 + nt) * 512);
            #pragma unroll
            for (int i = 0; i < 4; ++i)
                #pragma unroll
                for (int nt = 0; nt < 2; ++nt)
                    acc[i * 2 + nt] = __builtin_amdgcn_mfma_f32_16x16x32_bf16(af[i], bf[nt], acc[i * 2 + nt], 0, 0, 0);
        }
    }
    // ---- slab 6: self term
    for (int ks = 0; ks < 16; ++ks) {
        short8 af[4], bf[2];
        #pragma unroll
        for (int i = 0; i < 4; ++i)
            af[i] = *(const short8*)(xb_base + (size_t)(i * 16 + l15) * 512 + ks * 32 + lq * 8);
        #pragma unroll
        for (int nt = 0; nt < 2; ++nt)
            bf[nt] = *(const short8*)(wbase + (size_t)(96 + ks) * 16384 + (size_t)(cf0 + nt) * 512);
        #pragma unroll
        for (int i = 0; i < 4; ++i)
            #pragma unroll
            for (int nt = 0; nt < 2; ++nt)
                acc[i * 2 + nt] = __builtin_amdgcn_mfma_f32_16x16x32_bf16(af[i], bf[nt], acc[i * 2 + nt], 0, 0, 0);
    }
    // ---- epilogue: relu -> outT (frag layout) + outR (rows 48..63 row-major)
    #pragma unroll
    for (int i = 0; i < 4; ++i)
        #pragma unroll
        for (int nt = 0; nt < 2; ++nt) {
            short4v pk;
            #pragma unroll
            for (int reg = 0; reg < 4; ++reg) pk[reg] = (short)f2bf(fmaxf(acc[i * 2 + nt][reg], 0.f));
            size_t a = (size_t)b * 32768 + (size_t)(i >> 1) * 16384 + (size_t)(cf0 + nt) * 512
                     + (size_t)((i & 1) * 2 + (lq >> 1)) * 128 + (size_t)l15 * 8 + (lq & 1) * 4;
            *(short4v*)(outT + a) = pk;
            if (i == 3) {
                int n = nh * 256 + w * 32 + nt * 16 + l15;
                #pragma unroll
                for (int reg = 0; reg < 4; ++reg)
                    outR[((size_t)b * 16 + lq * 4 + reg) * 512 + n] = (u16)pk[reg];
            }
        }
}

// ---------------------------------------------------------------------------
// Final RGCN layer (rows 48..63), v16 = v15 (validated round 10) with the
// block index decode INVERTED: b = blockIdx&255, cb = blockIdx>>8.
// Rationale [T1-style XCD locality]: round-robin block->XCD gives
// XCD = blockIdx%8. Old decode (b*8+cb) pinned cb per XCD -> every XCD
// streamed the ENTIRE 16.8 MB xT (FETCH 96 MB, fetch-bound 132 µs).
// New decode pins b%8 per XCD -> each XCD's xT working set = 32 batches
// x 64 KB = 2.1 MB, fits its 4 MB L2; wcat (3.67 MB) fetched once per XCD.
__global__ __launch_bounds__(64)
void k_klast(const u16* __restrict__ xT, const u16* __restrict__ xr,
             const u16* __restrict__ aq1, const u16* __restrict__ wc, int mode,
             u16* __restrict__ o16, float* __restrict__ o32) {
    int b = blockIdx.x & 255, cb = blockIdx.x >> 8;
    int lane = threadIdx.x;
    int l15 = lane & 15, lq = lane >> 4;
    const int PS = 40;                         // tp row stride (16B-aligned reads)
    __shared__ __align__(16) u16 tp[16 * 40];  // 1280 B

    const u16* xTb   = xT + (size_t)b * 32768 + (size_t)lane * 8;
    const u16* wbase = wc + (size_t)lane * 8;
    const u16* aqb   = aq1 + (size_t)b * 6 * 1024 + (size_t)lane * 8;

    // preload A_q rows-48..63 frags (frag6: k 0..31, frag7: k 32..63)
    short8 aqf[12];
    #pragma unroll
    for (int q = 0; q < 6; ++q) {
        aqf[q * 2 + 0] = *(const short8*)(aqb + (size_t)q * 1024);
        aqf[q * 2 + 1] = *(const short8*)(aqb + (size_t)q * 1024 + 512);
    }

    floatx4 acc[4];
    #pragma unroll
    for (int i = 0; i < 4; ++i) acc[i] = (floatx4)(0.f);

    // self slab: xr rows 48..63 row-major x wcat slab 6 (validated pattern)
    for (int ks = 0; ks < 16; ++ks) {
        short8 af = *(const short8*)(xr + ((size_t)b * 16 + l15) * 512 + ks * 32 + lq * 8);
        #pragma unroll
        for (int nt = 0; nt < 4; ++nt) {
            short8 bf = *(const short8*)(wbase + (size_t)(96 + ks) * 16384 + (size_t)(cb * 4 + nt) * 512);
            acc[nt] = __builtin_amdgcn_mfma_f32_16x16x32_bf16(af, bf, acc[nt], 0, 0, 0);
        }
    }

    for (int p = 0; p < 16; ++p) {      // h-pair = 32 h-cols = stage-B k-frag p
        // xb frags for h-tiles 2p, 2p+1 (coalesced, round-8-validated layout)
        short8 xb00 = *(const short8*)(xTb + (size_t)(2 * p + 0) * 512);
        short8 xb01 = *(const short8*)(xTb + 16384 + (size_t)(2 * p + 0) * 512);
        short8 xb10 = *(const short8*)(xTb + (size_t)(2 * p + 1) * 512);
        short8 xb11 = *(const short8*)(xTb + 16384 + (size_t)(2 * p + 1) * 512);
        for (int q = 0; q < 6; ++q) {
            // stage A: two C-tiles of T'_q (rows 0..15 = nodes 48..63)
            floatx4 tz0 = (floatx4)(0.f), tz1 = (floatx4)(0.f);
            tz0 = __builtin_amdgcn_mfma_f32_16x16x32_bf16(aqf[q * 2 + 0], xb00, tz0, 0, 0, 0);
            tz0 = __builtin_amdgcn_mfma_f32_16x16x32_bf16(aqf[q * 2 + 1], xb01, tz0, 0, 0, 0);
            tz1 = __builtin_amdgcn_mfma_f32_16x16x32_bf16(aqf[q * 2 + 0], xb10, tz1, 0, 0, 0);
            tz1 = __builtin_amdgcn_mfma_f32_16x16x32_bf16(aqf[q * 2 + 1], xb11, tz1, 0, 0, 0);
            // C layout: tz_t[reg] = T'[m = lq*4+reg][h = 32p + t*16 + l15]
            #pragma unroll
            for (int reg = 0; reg < 4; ++reg) {
                tp[(lq * 4 + reg) * PS + l15]      = f2bf(tz0[reg]);
                tp[(lq * 4 + reg) * PS + 16 + l15] = f2bf(tz1[reg]);
            }
            __syncthreads();   // 1-wave: cheap; order writes before read
            short8 af = *(const short8*)&tp[l15 * PS + lq * 8];
            __syncthreads();   // read done before next q overwrites
            // stage B: acc += T'_q[:, 32p..32p+31] @ B_q[k-frag p, col band]
            #pragma unroll
            for (int nt = 0; nt < 4; ++nt) {
                short8 bf = *(const short8*)(wbase + (size_t)(q * 16 + p) * 16384 + (size_t)(cb * 4 + nt) * 512);
                acc[nt] = __builtin_amdgcn_mfma_f32_16x16x32_bf16(af, bf, acc[nt], 0, 0, 0);
            }
        }
    }

    // epilogue (validated): m = 48 + lq*4 + reg, n = cb*64 + nt*16 + l15
    #pragma unroll
    for (int nt = 0; nt < 4; ++nt) {
        int n = cb * 64 + nt * 16 + l15;
        #pragma unroll
        for (int reg = 0; reg < 4; ++reg) {
            int m = 48 + lq * 4 + reg;
            float v = acc[nt][reg];
            if (mode == 1) {
                if (m >= 58 && m <= 61)
                    o16[((size_t)b * 64 + m) * 512 + n] = f2bf(1.f / (1.f + __expf(-v)));
            } else {
                if (m == 60 || m == 62) {
                    int slot = (m == 60) ? (b * 2) : (b * 2 + 1);
                    o32[(size_t)slot * 512 + n] = 1.f / (1.f + __expf(-v));
                }
            }
        }
    }
}

// logits = [black|white] @ type_W^T + type_b  (unchanged, validated)
__global__ void k_final(const float* __restrict__ t2, const float* __restrict__ tW,
                        const float* __restrict__ tb, float* __restrict__ outp) {
    int b = blockIdx.x, l = threadIdx.x;   // 64 threads
    float a[11];
    #pragma unroll
    for (int j = 0; j < 11; ++j) a[j] = 0.f;
    for (int it = 0; it < 16; ++it) {
        int h = it * 64 + l;
        float c = (h < 512) ? t2[(b * 2 + 1) * 512 + h] : t2[(b * 2 + 0) * 512 + (h - 512)];
        #pragma unroll
        for (int j = 0; j < 11; ++j) a[j] += c * tW[j * 1024 + h];
    }
    #pragma unroll
    for (int j = 0; j < 11; ++j) {
        float v = a[j];
        for (int off = 32; off > 0; off >>= 1) v += __shfl_down(v, off, 64);
        if (l == 0) outp[b * 11 + j] = v + tb[j];
    }
}

// ---------------------------------------------------------------------------
extern "C" void kernel_launch(void* const* d_in, const int* in_sizes, int n_in,
                              void* d_out, int out_size, void* d_ws, size_t ws_size,
                              hipStream_t stream) {
    const int*   player = (const int*)d_in[0];
    const float* enc    = (const float*)d_in[2];
    const int*   adjm   = (const int*)d_in[3];
    const float* pAx    = (const float*)d_in[4];
    const float* pAy    = (const float*)d_in[5];
    const float* pBx    = (const float*)d_in[6];
    const float* pBy    = (const float*)d_in[7];
    const float* emb    = (const float*)d_in[8];
    const float* cW     = (const float*)d_in[9];
    const float* cb     = (const float*)d_in[10];
    const float* inW    = (const float*)d_in[11];
    const float* inb    = (const float*)d_in[12];
    const float* basis0 = (const float*)d_in[13];
    const float* comb0  = (const float*)d_in[14];
    const float* self0  = (const float*)d_in[15];
    const float* basis1 = (const float*)d_in[16];
    const float* comb1  = (const float*)d_in[17];
    const float* self1  = (const float*)d_in[18];
    const float* typeW  = (const float*)d_in[19];
    const float* typeb  = (const float*)d_in[20];

    char* ws = (char*)d_ws;
    size_t off = 0;
    auto alloc = [&](size_t bytes) -> void* {
        void* p = ws + off;
        off = (off + bytes + 255) & ~(size_t)255;
        return p;
    };
    // Workspace (~80.8 MB, under proven 89.1):
    //   mi1 (prep..layer1), aliased by t2 (klast2..final)
    //   x12T/x12r: layer->klast frag + rows48-63, reused both passes
    //   aq0 full (k_layer), aq1 compact frags 6,7 (klast); regenerated mid-run
    u16* mi1   = (u16*)alloc(256UL * 64 * 512 * 2);
    u16* mi2   = (u16*)alloc(256UL * 64 * 512 * 2);
    u16* x12T  = (u16*)alloc(256UL * 32768 * 2);
    u16* x12r  = (u16*)alloc(256UL * 16 * 512 * 2);
    u16* aq0   = (u16*)alloc(256UL * 6 * 4096 * 2);
    u16* aq1   = (u16*)alloc(256UL * 6 * 1024 * 2);
    u16* wcat0 = (u16*)alloc(3584UL * 512 * 2);
    u16* wcat1 = (u16*)alloc(3584UL * 512 * 2);
    u64* mm0   = (u64*)alloc(256UL * 12 * 64 * 8);
    u64* mm1   = (u64*)alloc(256UL * 12 * 64 * 8);
    float* t2  = (float*)mi1;     // mi1 dead after pass-1 k_layer

    k_wcat2<<<896, 256, 0, stream>>>(basis0, self0, basis1, self1, wcat0, wcat1);
    k_masks<<<3072, 64, 0, stream>>>(adjm, mm0, mm1);
    k_aqexp<<<2048, 256, 0, stream>>>(mm0, comb0, comb1, aq0, aq1);
    k_castprep<<<4096, 256, 0, stream>>>(enc, player, pAx, pAy, pBx, pBy, emb, cW, cb, inW, inb, mi1, mi2);

    // pass 1
    k_layer<<<512, 512, 0, stream>>>(mi1, aq0, wcat0, x12T, x12r);
    k_klast<<<2048, 64, 0, stream>>>(x12T, x12r, aq1, wcat1, 1, mi2, nullptr);
    // regenerate weighted adjacency for the pruned pass-2 graph
    k_aqexp<<<2048, 256, 0, stream>>>(mm1, comb0, comb1, aq0, aq1);
    // pass 2
    k_layer<<<512, 512, 0, stream>>>(mi2, aq0, wcat0, x12T, x12r);
    k_klast<<<2048, 64, 0, stream>>>(x12T, x12r, aq1, wcat1, 2, nullptr, t2);

    k_final<<<256, 64, 0, stream>>>(t2, typeW, typeb, (float*)d_out);
}

// Round 12
// 663.993 us; speedup vs baseline: 1.3042x; 1.0800x over previous
//
#include <hip/hip_runtime.h>
#include <hip/hip_bf16.h>

typedef unsigned short u16;
typedef unsigned long long u64;
typedef __attribute__((ext_vector_type(4))) short short4v;
typedef __attribute__((ext_vector_type(8))) short short8;
typedef __attribute__((ext_vector_type(4))) float floatx4;

__device__ __forceinline__ u16 f2bf(float f) {
    union { float f; unsigned u; } v; v.f = f;
    unsigned r = v.u + 0x7FFF + ((v.u >> 16) & 1);
    return (u16)(r >> 16);
}

// ---------------------------------------------------------------------------
// Wcat stacks for both layers in one dispatch (validated round 8).
// element (k,n) at: (k>>5)*16384 + (n>>4)*512 + ((k>>3)&3)*128 + (n&15)*8 + (k&7)
__global__ void k_wcat2(const float* __restrict__ b0, const float* __restrict__ s0,
                        const float* __restrict__ b1, const float* __restrict__ s1,
                        u16* __restrict__ wf0, u16* __restrict__ wf1) {
    int bi = blockIdx.x, t = threadIdx.x;
    const float* basis = (bi < 448) ? b0 : b1;
    const float* selfW = (bi < 448) ? s0 : s1;
    u16* wf = (bi < 448) ? wf0 : wf1;
    if (bi >= 448) bi -= 448;
    int kr = t >> 7;
    int nb = (t & 127) * 4;
    for (int it = 0; it < 4; ++it) {
        int k = bi * 8 + it * 2 + kr;
        float v0, v1, v2, v3;
        if (k < 3072) {
            int q = k >> 9, h = k & 511;
            const float4 bz = *(const float4*)(basis + ((size_t)(q * 512 + h)) * 512 + nb);
            v0 = bz.x; v1 = bz.y; v2 = bz.z; v3 = bz.w;
        } else {
            int kk = k - 3072;
            v0 = selfW[(size_t)(nb + 0) * 512 + kk];
            v1 = selfW[(size_t)(nb + 1) * 512 + kk];
            v2 = selfW[(size_t)(nb + 2) * 512 + kk];
            v3 = selfW[(size_t)(nb + 3) * 512 + kk];
        }
        float vv[4] = {v0, v1, v2, v3};
        for (int i = 0; i < 4; ++i) {
            int n = nb + i;
            wf[(size_t)(k >> 5) * 16384 + (n >> 4) * 512 + ((k >> 3) & 3) * 128 + (n & 15) * 8 + (k & 7)] = f2bf(vv[i]);
        }
    }
}

// ---------------------------------------------------------------------------
// Row masks via coalesced row reads + wave ballot (unchanged, validated).
__global__ void k_masks(const int* __restrict__ A, u64* __restrict__ m0, u64* __restrict__ m1) {
    int bi = blockIdx.x;          // b*12 + r
    int b = bi / 12, r = bi % 12;
    const int* Ab = A + (size_t)(b * 13 + (r + 1)) * 62 * 62;
    int lane = threadIdx.x;       // 0..63
    u64 my0 = 0, my1 = 0;
    for (int n = 0; n < 64; ++n) {
        int raw = 0;
        if (n < 62 && lane < 62) raw = (Ab[n * 62 + lane] != 0) ? 1 : 0;
        u64 b0 = __ballot(raw != 0);
        int v1 = 0;
        if (n < 63 && lane < 63) {
            int oi = (n == 62) ? 63 : n;
            int oj = (lane == 62) ? 63 : lane;
            v1 = (oi < 62 && oj < 62) ? raw : 0;
            int lo = (oi < oj) ? oi : oj, hi = (oi < oj) ? oj : oi;
            if (hi == lo + 2) {
                int p = (lo >> 1) & 1;
                int chp = ((lo & 1) == 0) ? (p ? 12 : 11) : (p ? 11 : 12);
                if (r + 1 == chp) v1 = 1;
            }
        }
        u64 b1 = __ballot(v1 != 0);
        if (lane == n) { my0 = b0; my1 = b1; }
    }
    m0[(size_t)bi * 64 + lane] = my0;
    m1[(size_t)bi * 64 + lane] = my1;
}

// ---------------------------------------------------------------------------
// Weighted adjacency expansion (validated):
//   set 0 (comb0, full 8 frags)  -> aq0[(b*6+q)*4096 + pos]
//   set 1 (comb1, frags 6,7 only)-> aq1[(b*6+q)*1024 + pos-3072]
__global__ void k_aqexp(const u64* __restrict__ msk, const float* __restrict__ comb0,
                        const float* __restrict__ comb1, u16* __restrict__ aq0,
                        u16* __restrict__ aq1) {
    int b = blockIdx.x >> 3, sp = blockIdx.x & 7;
    int t = threadIdx.x;
    __shared__ u64 sm[12 * 64];
    __shared__ float cmb[2][12][6];
    if (t < 72) { cmb[0][t / 6][t % 6] = comb0[t]; cmb[1][t / 6][t % 6] = comb1[t]; }
    for (int i = t; i < 768; i += 256) sm[i] = msk[(size_t)b * 768 + i];
    __syncthreads();
    #pragma unroll
    for (int ii2 = 0; ii2 < 2; ++ii2) {
        int pos = (sp * 2 + ii2) * 256 + t;
        int f = pos >> 9, lane = (pos >> 3) & 63, j = pos & 7;
        int row = ((f >> 1) << 4) + (lane & 15);
        int mb  = ((f & 1) << 5) + ((lane >> 4) << 3) + j;
        float bits[12];
        #pragma unroll
        for (int r = 0; r < 12; ++r) bits[r] = (float)((sm[r * 64 + row] >> mb) & 1ull);
        #pragma unroll
        for (int q = 0; q < 6; ++q) {
            float v0 = 0.f, v1 = 0.f;
            #pragma unroll
            for (int r = 0; r < 12; ++r) {
                v0 += bits[r] * cmb[0][r][q];
                v1 += bits[r] * cmb[1][r][q];
            }
            aq0[((size_t)b * 6 + q) * 4096 + pos] = f2bf(v0);
            if (f >= 6) aq1[((size_t)b * 6 + q) * 1024 + pos - 3072] = f2bf(v1);
        }
    }
}

// ---------------------------------------------------------------------------
// Fused cast + prep (validated round 8).
__global__ void k_castprep(const float* __restrict__ enc,
                           const int* __restrict__ player,
                           const float* __restrict__ pAx, const float* __restrict__ pAy,
                           const float* __restrict__ pBx, const float* __restrict__ pBy,
                           const float* __restrict__ emb, const float* __restrict__ cW,
                           const float* __restrict__ cb, const float* __restrict__ inW,
                           const float* __restrict__ inb,
                           u16* __restrict__ mi1, u16* __restrict__ mi2) {
    int t = threadIdx.x;
    if (blockIdx.x < 3840) {
        long long e = ((long long)blockIdx.x * 256 + t) * 8;
        int b = (int)(e / (60 * 512));
        int rm = (int)(e % (60 * 512));
        int n = rm / 512, h = rm % 512;
        float4 f0 = *(const float4*)(enc + e);
        float4 f1 = *(const float4*)(enc + e + 4);
        short8 pk;
        pk[0] = (short)f2bf(f0.x); pk[1] = (short)f2bf(f0.y);
        pk[2] = (short)f2bf(f0.z); pk[3] = (short)f2bf(f0.w);
        pk[4] = (short)f2bf(f1.x); pk[5] = (short)f2bf(f1.y);
        pk[6] = (short)f2bf(f1.z); pk[7] = (short)f2bf(f1.w);
        *(short8*)(mi1 + ((size_t)b * 64 + n) * 512 + h) = pk;
        if (n < 58) *(short8*)(mi2 + ((size_t)b * 64 + n) * 512 + h) = pk;
        return;
    }
    int b = blockIdx.x - 3840;
    __shared__ float feat[2][64];
    if (t < 64) {
        int j = t >> 5, d = t & 31;
        float X = j ? pBx[b] : pAx[b];
        float Y = j ? pBy[b] : pAy[b];
        feat[j][d] = fmaxf(cW[d * 2] * X + cW[d * 2 + 1] * Y + cb[d], 0.f);
        feat[j][32 + d] = emb[player[b * 2 + j] * 32 + d];
    }
    __syncthreads();
    for (int h = t; h < 512; h += 256) {
        float a0 = inb[h], a1 = inb[h];
        const float* wrow = inW + h * 64;
        #pragma unroll
        for (int d = 0; d < 64; ++d) {
            float wv = wrow[d];
            a0 += wv * feat[0][d];
            a1 += wv * feat[1][d];
        }
        u16 v0 = f2bf(a0), v1 = f2bf(a1);
        size_t base = (size_t)b * 64 * 512;
        mi1[base + 60 * 512 + h] = v0;
        mi1[base + 61 * 512 + h] = v1;
        mi1[base + 62 * 512 + h] = 0;
        mi1[base + 63 * 512 + h] = 0;
        mi2[base + 62 * 512 + h] = v1;
        mi2[base + 63 * 512 + h] = 0;
    }
}

// ---------------------------------------------------------------------------
// Full RGCN layer — EXACT round-5 v10 structure (proven 99.5 µs), epilogue
// writes outT (fragment layout, round-8-validated formula) + outR rows 48..63.
__global__ __launch_bounds__(512, 2)
void k_layer(const u16* __restrict__ x, const u16* __restrict__ aq,
             const u16* __restrict__ wc, u16* __restrict__ outT, u16* __restrict__ outR) {
    int b = blockIdx.x >> 1, nh = blockIdx.x & 1;
    int t = threadIdx.x, lane = t & 63, w = t >> 6;
    int l15 = lane & 15, lq = lane >> 4;
    const int TS = 520;
    __shared__ __align__(16) u16 T[64 * 520];

    const u16* xb_base = x + (size_t)b * 64 * 512;
    short8 xb[8];
    #pragma unroll
    for (int nt = 0; nt < 4; ++nt)
        #pragma unroll
        for (int kh = 0; kh < 2; ++kh) {
            int h = (w * 4 + nt) * 16 + l15;
            int j0 = kh * 32 + lq * 8;
            short8 v;
            #pragma unroll
            for (int jj = 0; jj < 8; ++jj)
                v[jj] = (short)xb_base[(size_t)(j0 + jj) * 512 + h];
            xb[nt * 2 + kh] = v;
        }

    floatx4 acc[8];                          // [i 0..3][nt 0..1]
    #pragma unroll
    for (int i = 0; i < 8; ++i) acc[i] = (floatx4)(0.f);

    const u16* aqb   = aq + (size_t)b * 6 * 4096 + (size_t)lane * 8;
    const u16* wbase = wc + (size_t)lane * 8;
    int cf0 = nh * 16 + w * 2;

    for (int q = 0; q < 6; ++q) {
        __syncthreads();
        // ---- stage A: T_q[m][h-band w] (full T, duplicated per col-half)
        for (int i = 0; i < 4; ++i) {
            short8 a0 = *(const short8*)(aqb + (size_t)q * 4096 + (i * 2 + 0) * 512);
            short8 a1 = *(const short8*)(aqb + (size_t)q * 4096 + (i * 2 + 1) * 512);
            #pragma unroll
            for (int nt = 0; nt < 4; ++nt) {
                floatx4 tz = (floatx4)(0.f);
                tz = __builtin_amdgcn_mfma_f32_16x16x32_bf16(a0, xb[nt * 2 + 0], tz, 0, 0, 0);
                tz = __builtin_amdgcn_mfma_f32_16x16x32_bf16(a1, xb[nt * 2 + 1], tz, 0, 0, 0);
                int hcol = (w * 4 + nt) * 16 + l15;
                int mrow = i * 16 + lq * 4;
                #pragma unroll
                for (int reg = 0; reg < 4; ++reg)
                    T[(mrow + reg) * TS + hcol] = f2bf(tz[reg]);
            }
        }
        __syncthreads();
        // ---- stage B: acc += T_q @ B_q  (own 32-col band)
        for (int ks = 0; ks < 16; ++ks) {
            short8 af[4], bf[2];
            #pragma unroll
            for (int i = 0; i < 4; ++i)
                af[i] = *(const short8*)&T[(i * 16 + l15) * TS + ks * 32 + lq * 8];
            #pragma unroll
            for (int nt = 0; nt < 2; ++nt)
                bf[nt] = *(const short8*)(wbase + (size_t)(q * 16 + ks) * 16384 + (size_t)(cf0 + nt) * 512);
            #pragma unroll
            for (int i = 0; i < 4; ++i)
                #pragma unroll
                for (int nt = 0; nt < 2; ++nt)
                    acc[i * 2 + nt] = __builtin_amdgcn_mfma_f32_16x16x32_bf16(af[i], bf[nt], acc[i * 2 + nt], 0, 0, 0);
        }
    }
    // ---- slab 6: self term
    for (int ks = 0; ks < 16; ++ks) {
        short8 af[4], bf[2];
        #pragma unroll
        for (int i = 0; i < 4; ++i)
            af[i] = *(const short8*)(xb_base + (size_t)(i * 16 + l15) * 512 + ks * 32 + lq * 8);
        #pragma unroll
        for (int nt = 0; nt < 2; ++nt)
            bf[nt] = *(const short8*)(wbase + (size_t)(96 + ks) * 16384 + (size_t)(cf0 + nt) * 512);
        #pragma unroll
        for (int i = 0; i < 4; ++i)
            #pragma unroll
            for (int nt = 0; nt < 2; ++nt)
                acc[i * 2 + nt] = __builtin_amdgcn_mfma_f32_16x16x32_bf16(af[i], bf[nt], acc[i * 2 + nt], 0, 0, 0);
    }
    // ---- epilogue: relu -> outT (frag layout) + outR (rows 48..63 row-major)
    #pragma unroll
    for (int i = 0; i < 4; ++i)
        #pragma unroll
        for (int nt = 0; nt < 2; ++nt) {
            short4v pk;
            #pragma unroll
            for (int reg = 0; reg < 4; ++reg) pk[reg] = (short)f2bf(fmaxf(acc[i * 2 + nt][reg], 0.f));
            size_t a = (size_t)b * 32768 + (size_t)(i >> 1) * 16384 + (size_t)(cf0 + nt) * 512
                     + (size_t)((i & 1) * 2 + (lq >> 1)) * 128 + (size_t)l15 * 8 + (lq & 1) * 4;
            *(short4v*)(outT + a) = pk;
            if (i == 3) {
                int n = nh * 256 + w * 32 + nt * 16 + l15;
                #pragma unroll
                for (int reg = 0; reg < 4; ++reg)
                    outR[((size_t)b * 16 + lq * 4 + reg) * 512 + n] = (u16)pk[reg];
            }
        }
}

// ---------------------------------------------------------------------------
// Final RGCN layer (rows 48..63), v17: ONE WAVE per (batch, 64-col band),
// XCD-local decode (b = blockIdx&255, validated round 11), and ZERO barriers.
// Round-11 diagnosis: 2 barriers x 96 iters each drained vmcnt(0) -> no load
// ever stayed in flight; 3.2k cycles/iter pure latency. A 1-wave block needs
// only s_waitcnt lgkmcnt(0) for LDS write->read ordering (+ sched_barrier(0)
// per skill rule #18 so hipcc can't hoist the read above the waitcnt).
// Restructure: per q, stage A writes the FULL T'_q (16x512, PS=520) across
// all 16 p-tiles, ONE lgkm sync, then 16 stage-B ks-steps. 12 syncs total;
// xb/wcat loads pipeline freely across iterations.
__global__ __launch_bounds__(64)
void k_klast(const u16* __restrict__ xT, const u16* __restrict__ xr,
             const u16* __restrict__ aq1, const u16* __restrict__ wc, int mode,
             u16* __restrict__ o16, float* __restrict__ o32) {
    int b = blockIdx.x & 255, cb = blockIdx.x >> 8;
    int lane = threadIdx.x;
    int l15 = lane & 15, lq = lane >> 4;
    const int PS = 520;                        // 1040 B row stride, 16B-aligned
    __shared__ __align__(16) u16 tp[16 * 520]; // 16,640 B

    const u16* xTb   = xT + (size_t)b * 32768 + (size_t)lane * 8;
    const u16* wbase = wc + (size_t)lane * 8;
    const u16* aqb   = aq1 + (size_t)b * 6 * 1024 + (size_t)lane * 8;

    // preload A_q rows-48..63 frags (frag6: k 0..31, frag7: k 32..63)
    short8 aqf[12];
    #pragma unroll
    for (int q = 0; q < 6; ++q) {
        aqf[q * 2 + 0] = *(const short8*)(aqb + (size_t)q * 1024);
        aqf[q * 2 + 1] = *(const short8*)(aqb + (size_t)q * 1024 + 512);
    }

    floatx4 acc[4];
    #pragma unroll
    for (int i = 0; i < 4; ++i) acc[i] = (floatx4)(0.f);

    // self slab: xr rows 48..63 row-major x wcat slab 6 (validated pattern)
    for (int ks = 0; ks < 16; ++ks) {
        short8 af = *(const short8*)(xr + ((size_t)b * 16 + l15) * 512 + ks * 32 + lq * 8);
        #pragma unroll
        for (int nt = 0; nt < 4; ++nt) {
            short8 bf = *(const short8*)(wbase + (size_t)(96 + ks) * 16384 + (size_t)(cb * 4 + nt) * 512);
            acc[nt] = __builtin_amdgcn_mfma_f32_16x16x32_bf16(af, bf, acc[nt], 0, 0, 0);
        }
    }

    for (int q = 0; q < 6; ++q) {
        // ---- stage A: full T'_q (rows 0..15 = nodes 48..63, cols 0..511)
        for (int p = 0; p < 16; ++p) {
            short8 xb00 = *(const short8*)(xTb + (size_t)(2 * p + 0) * 512);
            short8 xb01 = *(const short8*)(xTb + 16384 + (size_t)(2 * p + 0) * 512);
            short8 xb10 = *(const short8*)(xTb + (size_t)(2 * p + 1) * 512);
            short8 xb11 = *(const short8*)(xTb + 16384 + (size_t)(2 * p + 1) * 512);
            floatx4 tz0 = (floatx4)(0.f), tz1 = (floatx4)(0.f);
            tz0 = __builtin_amdgcn_mfma_f32_16x16x32_bf16(aqf[q * 2 + 0], xb00, tz0, 0, 0, 0);
            tz0 = __builtin_amdgcn_mfma_f32_16x16x32_bf16(aqf[q * 2 + 1], xb01, tz0, 0, 0, 0);
            tz1 = __builtin_amdgcn_mfma_f32_16x16x32_bf16(aqf[q * 2 + 0], xb10, tz1, 0, 0, 0);
            tz1 = __builtin_amdgcn_mfma_f32_16x16x32_bf16(aqf[q * 2 + 1], xb11, tz1, 0, 0, 0);
            // C layout: tz_t[reg] = T'[m = lq*4+reg][h = 32p + t*16 + l15]
            #pragma unroll
            for (int reg = 0; reg < 4; ++reg) {
                tp[(lq * 4 + reg) * PS + 32 * p + l15]      = f2bf(tz0[reg]);
                tp[(lq * 4 + reg) * PS + 32 * p + 16 + l15] = f2bf(tz1[reg]);
            }
        }
        // single-wave LDS write->read ordering (no barrier, no vmcnt drain)
        asm volatile("s_waitcnt lgkmcnt(0)" ::: "memory");
        __builtin_amdgcn_sched_barrier(0);
        // ---- stage B: acc += T'_q @ B_q (wave's 64-col band)
        for (int ks = 0; ks < 16; ++ks) {
            short8 af = *(const short8*)&tp[l15 * PS + ks * 32 + lq * 8];
            #pragma unroll
            for (int nt = 0; nt < 4; ++nt) {
                short8 bf = *(const short8*)(wbase + (size_t)(q * 16 + ks) * 16384 + (size_t)(cb * 4 + nt) * 512);
                acc[nt] = __builtin_amdgcn_mfma_f32_16x16x32_bf16(af, bf, acc[nt], 0, 0, 0);
            }
        }
        // reads complete before next q's stage A overwrites tp
        asm volatile("s_waitcnt lgkmcnt(0)" ::: "memory");
        __builtin_amdgcn_sched_barrier(0);
    }

    // epilogue (validated): m = 48 + lq*4 + reg, n = cb*64 + nt*16 + l15
    #pragma unroll
    for (int nt = 0; nt < 4; ++nt) {
        int n = cb * 64 + nt * 16 + l15;
        #pragma unroll
        for (int reg = 0; reg < 4; ++reg) {
            int m = 48 + lq * 4 + reg;
            float v = acc[nt][reg];
            if (mode == 1) {
                if (m >= 58 && m <= 61)
                    o16[((size_t)b * 64 + m) * 512 + n] = f2bf(1.f / (1.f + __expf(-v)));
            } else {
                if (m == 60 || m == 62) {
                    int slot = (m == 60) ? (b * 2) : (b * 2 + 1);
                    o32[(size_t)slot * 512 + n] = 1.f / (1.f + __expf(-v));
                }
            }
        }
    }
}

// logits = [black|white] @ type_W^T + type_b  (unchanged, validated)
__global__ void k_final(const float* __restrict__ t2, const float* __restrict__ tW,
                        const float* __restrict__ tb, float* __restrict__ outp) {
    int b = blockIdx.x, l = threadIdx.x;   // 64 threads
    float a[11];
    #pragma unroll
    for (int j = 0; j < 11; ++j) a[j] = 0.f;
    for (int it = 0; it < 16; ++it) {
        int h = it * 64 + l;
        float c = (h < 512) ? t2[(b * 2 + 1) * 512 + h] : t2[(b * 2 + 0) * 512 + (h - 512)];
        #pragma unroll
        for (int j = 0; j < 11; ++j) a[j] += c * tW[j * 1024 + h];
    }
    #pragma unroll
    for (int j = 0; j < 11; ++j) {
        float v = a[j];
        for (int off = 32; off > 0; off >>= 1) v += __shfl_down(v, off, 64);
        if (l == 0) outp[b * 11 + j] = v + tb[j];
    }
}

// ---------------------------------------------------------------------------
extern "C" void kernel_launch(void* const* d_in, const int* in_sizes, int n_in,
                              void* d_out, int out_size, void* d_ws, size_t ws_size,
                              hipStream_t stream) {
    const int*   player = (const int*)d_in[0];
    const float* enc    = (const float*)d_in[2];
    const int*   adjm   = (const int*)d_in[3];
    const float* pAx    = (const float*)d_in[4];
    const float* pAy    = (const float*)d_in[5];
    const float* pBx    = (const float*)d_in[6];
    const float* pBy    = (const float*)d_in[7];
    const float* emb    = (const float*)d_in[8];
    const float* cW     = (const float*)d_in[9];
    const float* cb     = (const float*)d_in[10];
    const float* inW    = (const float*)d_in[11];
    const float* inb    = (const float*)d_in[12];
    const float* basis0 = (const float*)d_in[13];
    const float* comb0  = (const float*)d_in[14];
    const float* self0  = (const float*)d_in[15];
    const float* basis1 = (const float*)d_in[16];
    const float* comb1  = (const float*)d_in[17];
    const float* self1  = (const float*)d_in[18];
    const float* typeW  = (const float*)d_in[19];
    const float* typeb  = (const float*)d_in[20];

    char* ws = (char*)d_ws;
    size_t off = 0;
    auto alloc = [&](size_t bytes) -> void* {
        void* p = ws + off;
        off = (off + bytes + 255) & ~(size_t)255;
        return p;
    };
    // Workspace (~80.8 MB, under proven 89.1):
    //   mi1 (prep..layer1), aliased by t2 (klast2..final)
    //   x12T/x12r: layer->klast frag + rows48-63, reused both passes
    //   aq0 full (k_layer), aq1 compact frags 6,7 (klast); regenerated mid-run
    u16* mi1   = (u16*)alloc(256UL * 64 * 512 * 2);
    u16* mi2   = (u16*)alloc(256UL * 64 * 512 * 2);
    u16* x12T  = (u16*)alloc(256UL * 32768 * 2);
    u16* x12r  = (u16*)alloc(256UL * 16 * 512 * 2);
    u16* aq0   = (u16*)alloc(256UL * 6 * 4096 * 2);
    u16* aq1   = (u16*)alloc(256UL * 6 * 1024 * 2);
    u16* wcat0 = (u16*)alloc(3584UL * 512 * 2);
    u16* wcat1 = (u16*)alloc(3584UL * 512 * 2);
    u64* mm0   = (u64*)alloc(256UL * 12 * 64 * 8);
    u64* mm1   = (u64*)alloc(256UL * 12 * 64 * 8);
    float* t2  = (float*)mi1;     // mi1 dead after pass-1 k_layer

    k_wcat2<<<896, 256, 0, stream>>>(basis0, self0, basis1, self1, wcat0, wcat1);
    k_masks<<<3072, 64, 0, stream>>>(adjm, mm0, mm1);
    k_aqexp<<<2048, 256, 0, stream>>>(mm0, comb0, comb1, aq0, aq1);
    k_castprep<<<4096, 256, 0, stream>>>(enc, player, pAx, pAy, pBx, pBy, emb, cW, cb, inW, inb, mi1, mi2);

    // pass 1
    k_layer<<<512, 512, 0, stream>>>(mi1, aq0, wcat0, x12T, x12r);
    k_klast<<<2048, 64, 0, stream>>>(x12T, x12r, aq1, wcat1, 1, mi2, nullptr);
    // regenerate weighted adjacency for the pruned pass-2 graph
    k_aqexp<<<2048, 256, 0, stream>>>(mm1, comb0, comb1, aq0, aq1);
    // pass 2
    k_layer<<<512, 512, 0, stream>>>(mi2, aq0, wcat0, x12T, x12r);
    k_klast<<<2048, 64, 0, stream>>>(x12T, x12r, aq1, wcat1, 2, nullptr, t2);

    k_final<<<256, 64, 0, stream>>>(t2, typeW, typeb, (float*)d_out);
}